// Round 1
// baseline (53.483 us; speedup 1.0000x reference)
//
#include <hip/hip_runtime.h>
#include <hip/hip_bf16.h>

#define FEATS 512
#define NW 5
#define NH 16

// One block per dst node i (512 blocks), one thread per head h (512 threads).
// att == softmax over batch dim of size 1 == exactly 1.0, so the attention MLP
// (W1..b3) is mathematically dead: x[f] = sum_w data[0,w,f].
__global__ __launch_bounds__(512) void gat_fused(
    const float* __restrict__ data,
    const float* __restrict__ gat_w,
    const float* __restrict__ a_src,
    const float* __restrict__ a_dst,
    const float* __restrict__ gat_bias,
    const float* __restrict__ F1,
    const float* __restrict__ fb1,
    const float* __restrict__ F2,
    const float* __restrict__ fb2,
    float* __restrict__ out)
{
    __shared__ float xs[FEATS];    // x[j] = window-summed node features
    __shared__ float feat[FEATS];  // feat_r row i
    __shared__ float part[NH][8];  // per-wave partials for the 16 dots
    __shared__ float hv[NH];

    const int h = threadIdx.x;   // head index
    const int i = blockIdx.x;    // dst node index

    // ---- x[f] = sum over the 5 windows (att == 1 exactly)
    float v = 0.f;
    #pragma unroll
    for (int w = 0; w < NW; ++w) v += data[w * FEATS + h];
    xs[h] = v;
    __syncthreads();

    // ---- GAT row i, head h:
    // logit(i,j,h) = leaky(x[i]*cd + x[j]*cs, 0.2)
    // leaky is positively homogeneous -> fold log2(e) into cs, cd and use exp2.
    const float LOG2E = 1.4426950408889634f;
    const float gwv = gat_w[h];
    const float cs = gwv * a_src[h] * LOG2E;
    const float cd = gwv * a_dst[h] * LOG2E;
    const float di = xs[i] * cd;

    float se = 0.f, sv = 0.f;
    #pragma unroll 8
    for (int j = 0; j < FEATS; ++j) {
        const float xj = xs[j];                           // wave-uniform -> LDS broadcast
        const float t  = fmaf(xj, cs, di);
        const float l  = fmaxf(t, 0.f) + 0.2f * fminf(t, 0.f);  // leaky(t, 0.2) (scaled)
        const float e  = exp2f(l);
        se += e;
        sv = fmaf(e, xj, sv);
    }
    // feat_r[i,h] = gw[h] * sum_j alpha*x[j] + bias[h]
    feat[h] = gwv * sv / se + gat_bias[h];
    __syncthreads();

    // ---- fcn: y[i,:] = sigmoid((feat . F1^T + fb1) . F2^T + fb2), 512->16->5
    const int lane = h & 63, wid = h >> 6;
    const float fv = feat[h];
    for (int k = 0; k < NH; ++k) {
        float p = fv * F1[k * FEATS + h];
        #pragma unroll
        for (int off = 32; off; off >>= 1) p += __shfl_xor(p, off);
        if (lane == 0) part[k][wid] = p;
    }
    __syncthreads();
    if (h < NH) {
        float s = fb1[h];
        #pragma unroll
        for (int w = 0; w < 8; ++w) s += part[h][w];
        hv[h] = s;
    }
    __syncthreads();
    if (h < 5) {
        float s = fb2[h];
        #pragma unroll
        for (int k = 0; k < NH; ++k) s = fmaf(hv[k], F2[h * NH + k], s);
        out[i * 5 + h] = 1.f / (1.f + __expf(-s));
    }
}

extern "C" void kernel_launch(void* const* d_in, const int* in_sizes, int n_in,
                              void* d_out, int out_size, void* d_ws, size_t ws_size,
                              hipStream_t stream) {
    (void)in_sizes; (void)n_in; (void)d_ws; (void)ws_size; (void)out_size;
    const float* data     = (const float*)d_in[0];
    // d_in[1..6] = W1,b1,W2,b2,W3,b3 — dead (att == 1 exactly)
    const float* gat_w    = (const float*)d_in[7];
    const float* a_src    = (const float*)d_in[8];
    const float* a_dst    = (const float*)d_in[9];
    const float* gat_bias = (const float*)d_in[10];
    const float* F1       = (const float*)d_in[11];
    const float* fb1      = (const float*)d_in[12];
    const float* F2       = (const float*)d_in[13];
    const float* fb2      = (const float*)d_in[14];

    gat_fused<<<FEATS, FEATS, 0, stream>>>(data, gat_w, a_src, a_dst, gat_bias,
                                           F1, fb1, F2, fb2, (float*)d_out);
}

// Round 2
// 35.084 us; speedup vs baseline: 1.5244x; 1.5244x over previous
//
#include <hip/hip_runtime.h>
#include <hip/hip_bf16.h>

#define FEATS 512
#define NW 5
#define NH 16

// ws layout (floats): [0,512) x_orig | [512,1024) x_sorted | [1024, 1024+512*512) feat (h-major)
#define WS_FLOATS_NEEDED (1024 + FEATS * FEATS)

// ---------------- Kernel A: window-sum + rank sort (1 block) ----------------
__global__ __launch_bounds__(512) void prep_sort(const float* __restrict__ data,
                                                 float* __restrict__ ws) {
    __shared__ __align__(16) float xs[FEATS];
    const int i = threadIdx.x;
    float v = 0.f;
    #pragma unroll
    for (int w = 0; w < NW; ++w) v += data[w * FEATS + i];
    xs[i] = v;
    __syncthreads();
    // rank = #{k: x_k < v} + #{k<i: x_k == v}  (stable -> permutation)
    int r = 0;
    const float4* x4 = (const float4*)xs;
    #pragma unroll 4
    for (int k4 = 0; k4 < FEATS / 4; ++k4) {
        float4 q = x4[k4];
        int kb = k4 * 4;
        r += (q.x < v) || (q.x == v && kb + 0 < i);
        r += (q.y < v) || (q.y == v && kb + 1 < i);
        r += (q.z < v) || (q.z == v && kb + 2 < i);
        r += (q.w < v) || (q.w == v && kb + 3 < i);
    }
    ws[i] = v;              // x_orig
    ws[FEATS + r] = v;      // x_sorted (ascending)
}

// ---------------- Kernel B: GAT row per head h (512 blocks) ----------------
// e(i,j) = exp(leaky(cd'*x_i + cs'*x_j, 0.2)); separable on each side of the kink.
// Sorted-prefix sums turn the j-reduction into a binary search + O(1) lookups.
__global__ __launch_bounds__(512) void gat_rows(const float* __restrict__ ws_in,
                                                const float* __restrict__ gat_w,
                                                const float* __restrict__ a_src,
                                                const float* __restrict__ a_dst,
                                                const float* __restrict__ gat_bias,
                                                float* __restrict__ feat) {
    __shared__ __align__(16) float xsrt[FEATS];
    __shared__ __align__(16) float xorig[FEATS];
    __shared__ float4 scanA[FEATS];
    __shared__ float4 scanB[FEATS];
    __shared__ float4 pre[FEATS + 1];

    const int t = threadIdx.x;
    const int h = blockIdx.x;

    xsrt[t]  = ws_in[FEATS + t];
    xorig[t] = ws_in[t];

    const float LOG2E = 1.4426950408889634f;
    const float gwv = gat_w[h];
    const float cs  = gwv * a_src[h] * LOG2E;   // full-slope src coeff (log2 domain)
    const float cd  = gwv * a_dst[h] * LOG2E;
    const float c2s = 0.2f * cs;
    __syncthreads();

    // per-element terms over sorted x
    const float xv = xsrt[t];
    const float p1 = __builtin_amdgcn_exp2f(cs * xv);
    const float p2 = __builtin_amdgcn_exp2f(c2s * xv);
    scanA[t] = make_float4(p1, p2, xv * p1, xv * p2);
    __syncthreads();

    // Hillis-Steele inclusive scan on float4 (9 passes, ping-pong)
    float4* src = scanA;
    float4* dst = scanB;
    for (int off = 1; off < FEATS; off <<= 1) {
        float4 v = src[t];
        if (t >= off) {
            float4 u = src[t - off];
            v.x += u.x; v.y += u.y; v.z += u.z; v.w += u.w;
        }
        dst[t] = v;
        __syncthreads();
        float4* tmp = src; src = dst; dst = tmp;
    }
    // exclusive prefix: pre[k] = sum_{m<k}, pre[512] = totals
    pre[t + 1] = src[t];
    if (t == 0) pre[0] = make_float4(0.f, 0.f, 0.f, 0.f);
    __syncthreads();

    // epilogue: thread t = dst node i
    const float xi = xorig[t];
    const float d  = cd * xi;
    const bool csn = (cs >= 0.f);
    // find m = first index where pred true (pred monotone nondecreasing in k):
    //   csn:  pred(k) = (cs*xsrt[k] + d >= 0)   -> full-slope set = [m,512)
    //   !csn: pred(k) = (cs*xsrt[k] + d <  0)   -> full-slope set = [0,m)
    int m = 0;
    #pragma unroll
    for (int step = 256; step; step >>= 1) {
        int cand = m + step;
        float tt = fmaf(xsrt[cand - 1], cs, d);
        bool p = csn ? (tt >= 0.f) : (tt < 0.f);
        if (!p) m = cand;
    }
    const float4 P = pre[m];
    const float4 T = pre[FEATS];
    const float A1 = __builtin_amdgcn_exp2f(d);
    const float A2 = __builtin_amdgcn_exp2f(0.2f * d);
    float Se, Sv;
    if (csn) {
        Se = A1 * (T.x - P.x) + A2 * P.y;
        Sv = A1 * (T.z - P.z) + A2 * P.w;
    } else {
        Se = A1 * P.x + A2 * (T.y - P.y);
        Sv = A1 * P.z + A2 * (T.w - P.w);
    }
    feat[h * FEATS + t] = gwv * (Sv / Se) + gat_bias[h];
}

// ---------------- Kernel C: 512->16->5 MLP + sigmoid (512 blocks) ----------------
__global__ __launch_bounds__(512) void mlp_out(const float* __restrict__ feat,
                                               const float* __restrict__ F1,
                                               const float* __restrict__ fb1,
                                               const float* __restrict__ F2,
                                               const float* __restrict__ fb2,
                                               float* __restrict__ out) {
    __shared__ float part[NH][8];
    __shared__ float hv[NH];
    const int h = threadIdx.x;
    const int i = blockIdx.x;
    const float fv = feat[h * FEATS + i];
    const int lane = h & 63, wid = h >> 6;
    for (int k = 0; k < NH; ++k) {
        float p = fv * F1[k * FEATS + h];
        #pragma unroll
        for (int off = 32; off; off >>= 1) p += __shfl_xor(p, off);
        if (lane == 0) part[k][wid] = p;
    }
    __syncthreads();
    if (h < NH) {
        float s = fb1[h];
        #pragma unroll
        for (int w = 0; w < 8; ++w) s += part[h][w];
        hv[h] = s;
    }
    __syncthreads();
    if (h < 5) {
        const float LOG2E = 1.4426950408889634f;
        float s = fb2[h];
        #pragma unroll
        for (int k = 0; k < NH; ++k) s = fmaf(hv[k], F2[h * NH + k], s);
        out[i * 5 + h] = 1.f / (1.f + __builtin_amdgcn_exp2f(-s * LOG2E));
    }
}

// ---------------- Fallback: fused O(N^3) kernel (if ws too small) ----------------
__global__ __launch_bounds__(512) void gat_fused_fb(
    const float* __restrict__ data,
    const float* __restrict__ gat_w, const float* __restrict__ a_src,
    const float* __restrict__ a_dst, const float* __restrict__ gat_bias,
    const float* __restrict__ F1, const float* __restrict__ fb1,
    const float* __restrict__ F2, const float* __restrict__ fb2,
    float* __restrict__ out)
{
    __shared__ __align__(16) float xs[FEATS];
    __shared__ float feat[FEATS];
    __shared__ float part[NH][8];
    __shared__ float hv[NH];
    const int h = threadIdx.x;
    const int i = blockIdx.x;
    float v = 0.f;
    #pragma unroll
    for (int w = 0; w < NW; ++w) v += data[w * FEATS + h];
    xs[h] = v;
    __syncthreads();
    const float LOG2E = 1.4426950408889634f;
    const float gwv = gat_w[h];
    const float cs = gwv * a_src[h] * LOG2E;
    const float cd = gwv * a_dst[h] * LOG2E;
    const float di = xs[i] * cd;
    float se = 0.f, sv = 0.f;
    const float4* x4 = (const float4*)xs;
    for (int j4 = 0; j4 < FEATS / 4; ++j4) {
        float4 q = x4[j4];
        #pragma unroll
        for (int u = 0; u < 4; ++u) {
            float xj = (u == 0) ? q.x : (u == 1) ? q.y : (u == 2) ? q.z : q.w;
            float tt = fmaf(xj, cs, di);
            float l  = fmaxf(tt, 0.2f * tt);
            float e  = __builtin_amdgcn_exp2f(l);
            se += e;
            sv = fmaf(e, xj, sv);
        }
    }
    feat[h] = gwv * sv / se + gat_bias[h];
    __syncthreads();
    const int lane = h & 63, wid = h >> 6;
    const float fv = feat[h];
    for (int k = 0; k < NH; ++k) {
        float p = fv * F1[k * FEATS + h];
        #pragma unroll
        for (int off = 32; off; off >>= 1) p += __shfl_xor(p, off);
        if (lane == 0) part[k][wid] = p;
    }
    __syncthreads();
    if (h < NH) {
        float s = fb1[h];
        #pragma unroll
        for (int w = 0; w < 8; ++w) s += part[h][w];
        hv[h] = s;
    }
    __syncthreads();
    if (h < 5) {
        float s = fb2[h];
        #pragma unroll
        for (int k = 0; k < NH; ++k) s = fmaf(hv[k], F2[h * NH + k], s);
        out[i * 5 + h] = 1.f / (1.f + __builtin_amdgcn_exp2f(-s * LOG2E));
    }
}

extern "C" void kernel_launch(void* const* d_in, const int* in_sizes, int n_in,
                              void* d_out, int out_size, void* d_ws, size_t ws_size,
                              hipStream_t stream) {
    (void)in_sizes; (void)n_in; (void)out_size;
    const float* data     = (const float*)d_in[0];
    // d_in[1..6] = W1,b1,W2,b2,W3,b3 — dead (softmax over batch dim of size 1 == 1)
    const float* gat_w    = (const float*)d_in[7];
    const float* a_src    = (const float*)d_in[8];
    const float* a_dst    = (const float*)d_in[9];
    const float* gat_bias = (const float*)d_in[10];
    const float* F1       = (const float*)d_in[11];
    const float* fb1      = (const float*)d_in[12];
    const float* F2       = (const float*)d_in[13];
    const float* fb2      = (const float*)d_in[14];
    float* out = (float*)d_out;

    if (ws_size >= (size_t)WS_FLOATS_NEEDED * sizeof(float)) {
        float* ws   = (float*)d_ws;
        float* featp = ws + 1024;
        prep_sort<<<1, FEATS, 0, stream>>>(data, ws);
        gat_rows<<<FEATS, FEATS, 0, stream>>>(ws, gat_w, a_src, a_dst, gat_bias, featp);
        mlp_out<<<FEATS, FEATS, 0, stream>>>(featp, F1, fb1, F2, fb2, out);
    } else {
        gat_fused_fb<<<FEATS, FEATS, 0, stream>>>(data, gat_w, a_src, a_dst, gat_bias,
                                                  F1, fb1, F2, fb2, out);
    }
}

// Round 3
// 23.415 us; speedup vs baseline: 2.2842x; 1.4984x over previous
//
#include <hip/hip_runtime.h>
#include <hip/hip_bf16.h>

#define FEATS 512
#define NW 5
#define NH 16

// ws layout (floats): [0,512) x_orig | [512,1024) x_sorted | [1024, 1024+512*512) feat_t (i-major)
#define WS_FLOATS_NEEDED (1024 + FEATS * FEATS)

// ---------------- Kernel A: window-sum + parallel rank sort (64 blocks) ----------------
// One wave per dst element i: count rank over all 512 j's (8 per lane) + shfl reduce.
__global__ __launch_bounds__(512) void prep_sort(const float* __restrict__ data,
                                                 float* __restrict__ ws) {
    __shared__ float xs[FEATS];
    const int t = threadIdx.x;
    float v = 0.f;
    #pragma unroll
    for (int w = 0; w < NW; ++w) v += data[w * FEATS + t];
    xs[t] = v;
    __syncthreads();

    const int wid = t >> 6, lane = t & 63;
    const int i = blockIdx.x * 8 + wid;
    const float vi = xs[i];               // wave-uniform -> LDS broadcast
    int r = 0;
    #pragma unroll
    for (int u = 0; u < 8; ++u) {
        const int j = u * 64 + lane;      // stride-1 per lane -> conflict-free
        const float xj = xs[j];
        r += (xj < vi) || (xj == vi && j < i);   // stable -> rank is a permutation
    }
    #pragma unroll
    for (int off = 32; off; off >>= 1) r += __shfl_xor(r, off);
    if (lane == 0) ws[FEATS + r] = vi;    // x_sorted ascending
    if (blockIdx.x == 0) ws[t] = xs[t];   // x_orig
}

// ---------------- Kernel B: GAT row per head h (512 blocks) ----------------
// e(i,j) = exp(leaky(cd*x_i + cs*x_j, 0.2)) is separable on each side of the kink;
// sorted-prefix sums turn the j-reduction into a binary search + O(1) lookups.
// Prefix sums built with a register shfl_up wave scan (no LDS ping-pong).
__global__ __launch_bounds__(512) void gat_rows(const float* __restrict__ ws_in,
                                                const float* __restrict__ gat_w,
                                                const float* __restrict__ a_src,
                                                const float* __restrict__ a_dst,
                                                const float* __restrict__ gat_bias,
                                                float* __restrict__ feat_t) {
    __shared__ float xsrt[FEATS];
    __shared__ float4 pre[FEATS + 1];
    __shared__ float4 wtot[8];

    const int t = threadIdx.x;
    const int h = blockIdx.x;
    const int lane = t & 63, wid = t >> 6;

    const float xv = ws_in[FEATS + t];    // sorted x
    const float xi = ws_in[t];            // original x (for dst term)
    xsrt[t] = xv;

    const float LOG2E = 1.4426950408889634f;
    const float gwv = gat_w[h];
    const float cs  = gwv * a_src[h] * LOG2E;
    const float cd  = gwv * a_dst[h] * LOG2E;

    const float p1 = __builtin_amdgcn_exp2f(cs * xv);
    const float p2 = __builtin_amdgcn_exp2f(0.2f * cs * xv);
    float4 s = make_float4(p1, p2, xv * p1, xv * p2);

    // 64-lane inclusive scan, register-only
    #pragma unroll
    for (int d = 1; d < 64; d <<= 1) {
        const float ax = __shfl_up(s.x, d);
        const float ay = __shfl_up(s.y, d);
        const float az = __shfl_up(s.z, d);
        const float aw = __shfl_up(s.w, d);
        if (lane >= d) { s.x += ax; s.y += ay; s.z += az; s.w += aw; }
    }
    if (lane == 63) wtot[wid] = s;
    __syncthreads();                      // also covers xsrt visibility
    float4 o = make_float4(0.f, 0.f, 0.f, 0.f);
    #pragma unroll
    for (int w = 0; w < 7; ++w) {
        if (w < wid) {
            const float4 u = wtot[w];     // wave-uniform -> broadcast
            o.x += u.x; o.y += u.y; o.z += u.z; o.w += u.w;
        }
    }
    s.x += o.x; s.y += o.y; s.z += o.z; s.w += o.w;
    pre[t + 1] = s;                       // exclusive prefix: pre[k] = sum_{m<k}
    if (t == 0) pre[0] = make_float4(0.f, 0.f, 0.f, 0.f);
    __syncthreads();

    // epilogue: thread t = dst node i
    const float d  = cd * xi;
    const bool csn = (cs >= 0.f);
    // m = first k where pred(k); pred monotone nondecreasing:
    //   csn:  pred(k) = (cs*xsrt[k] + d >= 0) -> full-slope set = [m,512)
    //   !csn: pred(k) = (cs*xsrt[k] + d <  0) -> full-slope set = [0,m)
    int m = 0;
    #pragma unroll
    for (int step = 256; step; step >>= 1) {
        const int cand = m + step;
        const float tt = fmaf(xsrt[cand - 1], cs, d);
        const bool p = csn ? (tt >= 0.f) : (tt < 0.f);
        if (!p) m = cand;
    }
    const float4 P = pre[m];
    const float4 T = pre[FEATS];
    const float A1 = __builtin_amdgcn_exp2f(d);
    const float A2 = __builtin_amdgcn_exp2f(0.2f * d);
    float Se, Sv;
    if (csn) {
        Se = A1 * (T.x - P.x) + A2 * P.y;
        Sv = A1 * (T.z - P.z) + A2 * P.w;
    } else {
        Se = A1 * P.x + A2 * (T.y - P.y);
        Sv = A1 * P.z + A2 * (T.w - P.w);
    }
    // transposed write: scatter on the store side so the MLP reads coalesced
    feat_t[t * FEATS + h] = gwv * (Sv / Se) + gat_bias[h];
}

// ---------------- Kernel C: 512->16->5 MLP + sigmoid (512 blocks) ----------------
__global__ __launch_bounds__(512) void mlp_out(const float* __restrict__ feat_t,
                                               const float* __restrict__ F1,
                                               const float* __restrict__ fb1,
                                               const float* __restrict__ F2,
                                               const float* __restrict__ fb2,
                                               float* __restrict__ out) {
    __shared__ float part[NH][8];
    __shared__ float hv[NH];
    const int h = threadIdx.x;
    const int i = blockIdx.x;
    const float fv = feat_t[i * FEATS + h];   // coalesced row read
    const int lane = h & 63, wid = h >> 6;
    for (int k = 0; k < NH; ++k) {
        float p = fv * F1[k * FEATS + h];
        #pragma unroll
        for (int off = 32; off; off >>= 1) p += __shfl_xor(p, off);
        if (lane == 0) part[k][wid] = p;
    }
    __syncthreads();
    if (h < NH) {
        float s = fb1[h];
        #pragma unroll
        for (int w = 0; w < 8; ++w) s += part[h][w];
        hv[h] = s;
    }
    __syncthreads();
    if (h < 5) {
        const float LOG2E = 1.4426950408889634f;
        float s = fb2[h];
        #pragma unroll
        for (int k = 0; k < NH; ++k) s = fmaf(hv[k], F2[h * NH + k], s);
        out[i * 5 + h] = 1.f / (1.f + __builtin_amdgcn_exp2f(-s * LOG2E));
    }
}

// ---------------- Fallback: fused O(N^3) kernel (if ws too small) ----------------
__global__ __launch_bounds__(512) void gat_fused_fb(
    const float* __restrict__ data,
    const float* __restrict__ gat_w, const float* __restrict__ a_src,
    const float* __restrict__ a_dst, const float* __restrict__ gat_bias,
    const float* __restrict__ F1, const float* __restrict__ fb1,
    const float* __restrict__ F2, const float* __restrict__ fb2,
    float* __restrict__ out)
{
    __shared__ __align__(16) float xs[FEATS];
    __shared__ float feat[FEATS];
    __shared__ float part[NH][8];
    __shared__ float hv[NH];
    const int h = threadIdx.x;
    const int i = blockIdx.x;
    float v = 0.f;
    #pragma unroll
    for (int w = 0; w < NW; ++w) v += data[w * FEATS + h];
    xs[h] = v;
    __syncthreads();
    const float LOG2E = 1.4426950408889634f;
    const float gwv = gat_w[h];
    const float cs = gwv * a_src[h] * LOG2E;
    const float cd = gwv * a_dst[h] * LOG2E;
    const float di = xs[h == h ? i : 0] * cd;
    float se = 0.f, sv = 0.f;
    const float4* x4 = (const float4*)xs;
    for (int j4 = 0; j4 < FEATS / 4; ++j4) {
        float4 q = x4[j4];
        #pragma unroll
        for (int u = 0; u < 4; ++u) {
            float xj = (u == 0) ? q.x : (u == 1) ? q.y : (u == 2) ? q.z : q.w;
            float tt = fmaf(xj, cs, di);
            float l  = fmaxf(tt, 0.2f * tt);
            float e  = __builtin_amdgcn_exp2f(l);
            se += e;
            sv = fmaf(e, xj, sv);
        }
    }
    feat[h] = gwv * sv / se + gat_bias[h];
    __syncthreads();
    const int lane = h & 63, wid = h >> 6;
    const float fv = feat[h];
    for (int k = 0; k < NH; ++k) {
        float p = fv * F1[k * FEATS + h];
        #pragma unroll
        for (int off = 32; off; off >>= 1) p += __shfl_xor(p, off);
        if (lane == 0) part[k][wid] = p;
    }
    __syncthreads();
    if (h < NH) {
        float s = fb1[h];
        #pragma unroll
        for (int w = 0; w < 8; ++w) s += part[h][w];
        hv[h] = s;
    }
    __syncthreads();
    if (h < 5) {
        float s = fb2[h];
        #pragma unroll
        for (int k = 0; k < NH; ++k) s = fmaf(hv[k], F2[h * NH + k], s);
        out[i * 5 + h] = 1.f / (1.f + __builtin_amdgcn_exp2f(-s * LOG2E));
    }
}

extern "C" void kernel_launch(void* const* d_in, const int* in_sizes, int n_in,
                              void* d_out, int out_size, void* d_ws, size_t ws_size,
                              hipStream_t stream) {
    (void)in_sizes; (void)n_in; (void)out_size;
    const float* data     = (const float*)d_in[0];
    // d_in[1..6] = W1,b1,W2,b2,W3,b3 — dead (softmax over batch dim of size 1 == 1)
    const float* gat_w    = (const float*)d_in[7];
    const float* a_src    = (const float*)d_in[8];
    const float* a_dst    = (const float*)d_in[9];
    const float* gat_bias = (const float*)d_in[10];
    const float* F1       = (const float*)d_in[11];
    const float* fb1      = (const float*)d_in[12];
    const float* F2       = (const float*)d_in[13];
    const float* fb2      = (const float*)d_in[14];
    float* out = (float*)d_out;

    if (ws_size >= (size_t)WS_FLOATS_NEEDED * sizeof(float)) {
        float* ws    = (float*)d_ws;
        float* featp = ws + 1024;
        prep_sort<<<64, FEATS, 0, stream>>>(data, ws);
        gat_rows<<<FEATS, FEATS, 0, stream>>>(ws, gat_w, a_src, a_dst, gat_bias, featp);
        mlp_out<<<FEATS, FEATS, 0, stream>>>(featp, F1, fb1, F2, fb2, out);
    } else {
        gat_fused_fb<<<FEATS, FEATS, 0, stream>>>(data, gat_w, a_src, a_dst, gat_bias,
                                                  F1, fb1, F2, fb2, out);
    }
}